// Round 8
// baseline (63.617 us; speedup 1.0000x reference)
//
#include <hip/hip_runtime.h>
#include <cstddef>

#define L1n 128
#define L2n 256
#define Kn  1024
#define BK  64
#define NSTEP (Kn / BK)   // 16

using frag_ab = __attribute__((ext_vector_type(8))) short;  // 8 bf16
using frag_cd = __attribute__((ext_vector_type(4))) float;  // 4 f32

// RNE f32->bf16 pair pack (low, high)
__device__ __forceinline__ unsigned pack_bf16(float x, float y) {
    unsigned ux = __float_as_uint(x);
    ux = (ux + 0x7FFFu + ((ux >> 16) & 1u)) >> 16;
    unsigned uy = __float_as_uint(y);
    uy = (uy + 0x7FFFu + ((uy >> 16) & 1u)) & 0xFFFF0000u;
    return ux | uy;
}

// ---------------- Kernel 1: fused row-norm + bf16-MFMA GEMM + dist ----------------
// TRAFFIC-HALVING round: tile 128x128 (BM = full M), grid = 64 batches x 2
// n-halves = 128 blocks, 512 threads (8 waves, 2Mx4N; wave-tile 64x32).
// Read traffic: A x2 + B x1 = 128 MB (was 256 MB with 64x64 tiles) -- all
// 64x64 variants measured 40+-3us = 6.4 TB/s effective on 256 MB, i.e.
// traffic-bound. Operand-swapped MFMA -> coalesced transposed stores
// dist_t[b][col][row] for the 2.4us dtw reader.
__global__ __launch_bounds__(512) void gemm_dist_kernel(
    const float* __restrict__ seq1,
    const float* __restrict__ seq2,
    float* __restrict__ dist)
{
    __shared__ __align__(16) unsigned char sA[2][128 * 128];  // 128 rows x 128 B (64 bf16)
    __shared__ __align__(16) unsigned char sB[2][128 * 128];
    __shared__ float sInvA[128];
    __shared__ float sInvB[128];

    // bijective XCD-chunk swizzle (128 % 8 == 0): a batch's 2 blocks share an XCD
    const int wg   = ((blockIdx.x & 7) << 4) + (blockIdx.x >> 3);
    const int b    = wg >> 1;
    const int nt   = wg & 1;          // n-half: cols [nt*128, nt*128+128)
    const int t    = threadIdx.x;
    const int lane = t & 63;
    const int w    = t >> 6;          // 0..7
    const int wr   = w >> 2;          // 0..1: rows [wr*64, +64)
    const int wc   = w & 3;           // 0..3: cols [wc*32, +32)

    const int r = t >> 2;             // staging row 0..127 (both A and B)
    const int j = t & 3;              // staging chunk 0..3
    const int swz = (r & 7) << 4;

    const float4* pA = reinterpret_cast<const float4*>(
        seq1 + (size_t)b * (L1n * Kn) + (size_t)r * Kn) + j * 4;
    const float4* pB = reinterpret_cast<const float4*>(
        seq2 + (size_t)b * (L2n * Kn) + (size_t)(nt * 128 + r) * Kn) + j * 4;

    float ssA = 0.0f, ssB = 0.0f;
    frag_cd acc[2][4] = {};   // [nj][mi] (operand-swapped: reg-dim = col)

    float4 av[4], bv[4];

    auto issue = [&](int s) {
#pragma unroll
        for (int i = 0; i < 4; ++i) { av[i] = pA[s * 16 + i]; bv[i] = pB[s * 16 + i]; }
    };
    auto convert = [&](int buf) {
#pragma unroll
        for (int i = 0; i < 4; ++i) {
            ssA += av[i].x * av[i].x + av[i].y * av[i].y + av[i].z * av[i].z + av[i].w * av[i].w;
            ssB += bv[i].x * bv[i].x + bv[i].y * bv[i].y + bv[i].z * bv[i].z + bv[i].w * bv[i].w;
            const int kb = (j * 4 + i) * 8;   // byte offset of this f32x4 as bf16x4
            *reinterpret_cast<uint2*>(&sA[buf][r * 128 + (kb ^ swz)]) =
                make_uint2(pack_bf16(av[i].x, av[i].y), pack_bf16(av[i].z, av[i].w));
            *reinterpret_cast<uint2*>(&sB[buf][r * 128 + (kb ^ swz)]) =
                make_uint2(pack_bf16(bv[i].x, bv[i].y), pack_bf16(bv[i].z, bv[i].w));
        }
    };
    auto domfma = [&](int buf) {
#pragma unroll
        for (int kk = 0; kk < 2; ++kk) {
            const int kb = kk * 64 + ((lane >> 4) << 4);
            const int fswz = (lane & 7) << 4;
            const int ml = wr * 64 + (lane & 15);
            const int nl = wc * 32 + (lane & 15);
            frag_ab a0 = *reinterpret_cast<const frag_ab*>(&sA[buf][(ml +  0) * 128 + (kb ^ fswz)]);
            frag_ab a1 = *reinterpret_cast<const frag_ab*>(&sA[buf][(ml + 16) * 128 + (kb ^ fswz)]);
            frag_ab a2 = *reinterpret_cast<const frag_ab*>(&sA[buf][(ml + 32) * 128 + (kb ^ fswz)]);
            frag_ab a3 = *reinterpret_cast<const frag_ab*>(&sA[buf][(ml + 48) * 128 + (kb ^ fswz)]);
            frag_ab b0 = *reinterpret_cast<const frag_ab*>(&sB[buf][(nl +  0) * 128 + (kb ^ fswz)]);
            frag_ab b1 = *reinterpret_cast<const frag_ab*>(&sB[buf][(nl + 16) * 128 + (kb ^ fswz)]);
            // swapped: reg-dim = seq2 col, lane&15 = seq1 row
            acc[0][0] = __builtin_amdgcn_mfma_f32_16x16x32_bf16(b0, a0, acc[0][0], 0, 0, 0);
            acc[0][1] = __builtin_amdgcn_mfma_f32_16x16x32_bf16(b0, a1, acc[0][1], 0, 0, 0);
            acc[0][2] = __builtin_amdgcn_mfma_f32_16x16x32_bf16(b0, a2, acc[0][2], 0, 0, 0);
            acc[0][3] = __builtin_amdgcn_mfma_f32_16x16x32_bf16(b0, a3, acc[0][3], 0, 0, 0);
            acc[1][0] = __builtin_amdgcn_mfma_f32_16x16x32_bf16(b1, a0, acc[1][0], 0, 0, 0);
            acc[1][1] = __builtin_amdgcn_mfma_f32_16x16x32_bf16(b1, a1, acc[1][1], 0, 0, 0);
            acc[1][2] = __builtin_amdgcn_mfma_f32_16x16x32_bf16(b1, a2, acc[1][2], 0, 0, 0);
            acc[1][3] = __builtin_amdgcn_mfma_f32_16x16x32_bf16(b1, a3, acc[1][3], 0, 0, 0);
        }
    };

    // prologue
    issue(0);
    convert(0);

    for (int s = 0; s < NSTEP; ++s) {
        __syncthreads();
        if (s + 1 < NSTEP) issue(s + 1);
        domfma(s & 1);
        if (s + 1 < NSTEP) convert((s + 1) & 1);
    }

    // row sums of squares: threads 4r..4r+3 (same wave) share row r
    ssA += __shfl_xor(ssA, 1); ssA += __shfl_xor(ssA, 2);
    ssB += __shfl_xor(ssB, 1); ssB += __shfl_xor(ssB, 2);
    if (j == 0) { sInvA[r] = rsqrtf(ssA); sInvB[r] = rsqrtf(ssB); }
    __syncthreads();

    // epilogue: dist_t[b][col][row] = 1 - acc^T * invA * invB (coalesced: lane&15 = row)
    float* dbase = dist + (size_t)b * (L1n * L2n);
#pragma unroll
    for (int nj = 0; nj < 2; ++nj)
#pragma unroll
        for (int mi = 0; mi < 4; ++mi) {
            const int m_l = wr * 64 + mi * 16 + (lane & 15);
            const int n_b = wc * 32 + nj * 16 + ((lane >> 4) << 2);
            const float ia = sInvA[m_l];
#pragma unroll
            for (int reg = 0; reg < 4; ++reg) {
                const int n_l = n_b + reg;
                dbase[(size_t)(nt * 128 + n_l) * L1n + m_l] =
                    1.0f - acc[nj][mi][reg] * ia * sInvB[n_l];
            }
        }
}

// ---------------- Kernel 2: DTW lag-skewed column sweep, global-direct ----------------
// R4-proven (~2.4us): transposed dist_t[b][col][row], lane l owns rows 2l,2l+1,
// LAG=4 skew puts the shfl off the critical path; 16-deep float2 prefetch.
__global__ __launch_bounds__(64) void dtw_kernel(
    const float* __restrict__ dist, float* __restrict__ out)
{
    const int b    = blockIdx.x;
    const int lane = threadIdx.x;
    const float INF = 3.0e38f;
    const bool lane0 = (lane == 0);
    const float* base = dist + (size_t)b * (L1n * L2n) + 2 * lane;  // [col][row]

    float c0 = INF, c1 = INF;
    float sh0 = INF, sh1 = INF, sh2 = INF, sh3 = INF, sh4 = INF;

    auto ldval = [&](int tt) -> float2 {
        int jj = tt - 4 * lane;
        jj = jj < 0 ? 0 : (jj > L2n - 1 ? L2n - 1 : jj);
        return *reinterpret_cast<const float2*>(base + (size_t)jj * L1n);
    };

    auto step = [&](float2 d, bool t0) {
        float u = lane0 ? (t0 ? 0.0f : INF) : sh3;   // D(r0-1, jj)
        float g = lane0 ? INF : sh4;                  // D(r0-1, jj-1)
        float ugm = fminf(u, g);
        float n0 = d.x + fminf(c0, ugm);
        float n1 = d.y + fminf(fminf(c1, c0), n0);
        float snew = __shfl_up(n1, 1);
        sh4 = sh3; sh3 = sh2; sh2 = sh1; sh1 = sh0; sh0 = snew;
        c0 = n0; c1 = n1;
    };

    float2 pfA[8], pfB[8];
#pragma unroll
    for (int u = 0; u < 8; ++u) pfA[u] = ldval(u);
#pragma unroll
    for (int u = 0; u < 8; ++u) pfB[u] = ldval(8 + u);

#pragma unroll
    for (int u = 0; u < 8; ++u) step(pfA[u], u == 0);
#pragma unroll
    for (int u = 0; u < 8; ++u) pfA[u] = ldval(16 + u);

    int t = 8;
    for (int i = 0; i < 31; ++i) {    // t = 8 .. 503
        float2 curB[8];
#pragma unroll
        for (int u = 0; u < 8; ++u) curB[u] = pfB[u];
#pragma unroll
        for (int u = 0; u < 8; ++u) pfB[u] = ldval(t + 16 + u);
#pragma unroll
        for (int u = 0; u < 8; ++u) step(curB[u], false);

        float2 curA[8];
#pragma unroll
        for (int u = 0; u < 8; ++u) curA[u] = pfA[u];
#pragma unroll
        for (int u = 0; u < 8; ++u) pfA[u] = ldval(t + 24 + u);
#pragma unroll
        for (int u = 0; u < 8; ++u) step(curA[u], false);
        t += 16;
    }

#pragma unroll
    for (int u = 0; u < 4; ++u) step(pfB[u], false);

    // lane 63 finished (127,255) at t=507 -> c1
    if (lane == 63)
        out[b] = 1.0f / (1.0f + c1 * (1.0f / (float)(L1n + L2n)));
}

extern "C" void kernel_launch(void* const* d_in, const int* in_sizes, int n_in,
                              void* d_out, int out_size, void* d_ws, size_t ws_size,
                              hipStream_t stream) {
    const float* seq1 = (const float*)d_in[0];   // 64*128*1024 f32
    const float* seq2 = (const float*)d_in[1];   // 64*256*1024 f32
    float* out  = (float*)d_out;                 // 64 f32
    float* dist = (float*)d_ws;                  // 8 MB scratch (transposed dist)

    gemm_dist_kernel<<<dim3(128), dim3(512), 0, stream>>>(seq1, seq2, dist);
    dtw_kernel<<<dim3(64), dim3(64), 0, stream>>>(dist, out);
}